// Round 11
// baseline (454.130 us; speedup 1.0000x reference)
//
#include <hip/hip_runtime.h>
#include <math.h>

typedef _Float16 f16;
typedef f16 f16x8 __attribute__((ext_vector_type(8)));
typedef float f32x4 __attribute__((ext_vector_type(4)));

#define EPS_F16 0.0009765625f   // jnp.finfo(float16).eps

// B=8, N=2048, C=2048, H=16, D=128, M=B*N=16384, K=C=2048

// ---------------- fp32 -> fp16 cast, 8 elems/thread ----------------
__global__ __launch_bounds__(256) void k_cast8h(const float* __restrict__ in,
                                                f16* __restrict__ out,
                                                long long n8) {
  long long i = (long long)blockIdx.x * blockDim.x + threadIdx.x;
  if (i >= n8) return;
  const float4* in4 = (const float4*)in;
  float4 a = in4[i * 2];
  float4 b = in4[i * 2 + 1];
  f16x8 o;
  o[0] = (f16)a.x; o[1] = (f16)a.y; o[2] = (f16)a.z; o[3] = (f16)a.w;
  o[4] = (f16)b.x; o[5] = (f16)b.y; o[6] = (f16)b.z; o[7] = (f16)b.w;
  *(f16x8*)(out + i * 8) = o;
}

// ---------------- async global->LDS helper ----------------
__device__ __forceinline__ void gl2lds16(const void* g, void* l) {
  __builtin_amdgcn_global_load_lds(
      (const __attribute__((address_space(1))) void*)g,
      (__attribute__((address_space(3))) void*)l, 16, 0, 0);
}

// counted vmcnt wait + scheduling fence (NEVER drain to 0 in the main loop)
template <int VM>
__device__ __forceinline__ void wait_vm() {
  if constexpr (VM == 8)      asm volatile("s_waitcnt vmcnt(8)" ::: "memory");
  else if constexpr (VM == 4) asm volatile("s_waitcnt vmcnt(4)" ::: "memory");
  else                        asm volatile("s_waitcnt vmcnt(0)" ::: "memory");
  __builtin_amdgcn_sched_barrier(0);
}

// raw barrier with compiler memory fences on both sides (plain-C ds_reads must
// not migrate across; do NOT use __syncthreads() — it drains vmcnt(0))
__device__ __forceinline__ void pipe_barrier() {
  __builtin_amdgcn_sched_barrier(0);
  asm volatile("" ::: "memory");
  __builtin_amdgcn_s_barrier();
  asm volatile("" ::: "memory");
  __builtin_amdgcn_sched_barrier(0);
}

// ====== 256x256 GEMM, BK=32, 4-slot LDS pipeline (prefetch dist 3), 8 waves ====
// C = A (MxK) * Bm (NxK)^T, fp16 in. K=2048. Grid must be dim3(8, 64).
// st_16x32 XOR swizzle (zero bank conflicts, verified r5-r10). Counted vmcnt(8)
// keeps 2 tiles in flight across every barrier (r8 ledger, race-free over 2
// validations). NEW r11: each K-tile split into 2 sub-phases
// {ds_reads + 2 stage loads -> barrier -> setprio+16 MFMA -> barrier}
// (m201/m196 fine interleave; barriers only restrict the proven schedule).
// launch_bounds MUST stay (512,2): forcing 4 waves/EU spills the 128-VGPR
// accumulator (r9: 6x regression).
// MODE 0: Cout (fp32) row-major M x 2048          [final projection]
// MODE 1: Wout (fp16) (B,H,N,D) via LDS-transposed 128B-coalesced stores
//         + fused chunk partials of q^2 -> psum (q = fp16(w), scans exact in q)
template <int MODE>
__global__ __launch_bounds__(512, 2) void gemm256(const f16* __restrict__ A,
                                                  const f16* __restrict__ Bm,
                                                  float* __restrict__ Cout,
                                                  f16* __restrict__ Wout,
                                                  float* __restrict__ psum) {
  constexpr int K = 2048;
  constexpr int NT = K / 32;          // 64 K-tiles
  __shared__ alignas(16) char lds[131072];   // 4 slots x (A 16KB + B 16KB)
  const int t = threadIdx.x;
  const int lane = t & 63;
  const int wid = t >> 6;
  const int wm = wid >> 2;   // M-half owner (0..1)
  const int wn = wid & 3;    // N-quarter owner (0..3)

  // T1: XCD-aware chunked swizzle (bijective: 512 % 8 == 0)
  const int lin = blockIdx.y * 8 + blockIdx.x;     // gridDim.x == 8
  const int logical = (lin & 7) * 64 + (lin >> 3);
  const size_t bm = (size_t)(logical >> 3) * 256;
  const size_t bn = (size_t)(logical & 7) * 256;

  // staging source geometry (BK=32): thread t, chunk j in {0,1} writes LDS bytes
  // [j*8192 + t*16, +16) of the 16KB matrix region; source = involution image.
  const int sk = ((t & 3) * 8) ^ (((t >> 5) & 1) << 4);
  size_t aOff[2], bOff[2];
#pragma unroll
  for (int j = 0; j < 2; ++j) {
    int sr = j * 128 + (t >> 6) * 16 + ((t & 63) >> 2);
    aOff[j] = (bm + (size_t)sr) * K + sk;
    bOff[j] = (bn + (size_t)sr) * K + sk;
  }
  const int t16 = t * 16;

  // per-lane fragment byte offset within a 1024B subtile (same XOR involution)
  const int lbyte = (((lane & 15) * 64 + (lane >> 4) * 16) ^ ((lane & 8) << 2));

  f32x4 acc[8][4] = {};

  auto stage_tile = [&](int kt) {   // prologue only: all 4 loads at once
    char* base = lds + (kt & 3) * 32768;
    const size_t ko = (size_t)kt * 32;
#pragma unroll
    for (int j = 0; j < 2; ++j) {
      gl2lds16(A + aOff[j] + ko, base + j * 8192 + t16);
      gl2lds16(Bm + bOff[j] + ko, base + 16384 + j * 8192 + t16);
    }
  };

  // K-tile compute in 2 sub-phases; optionally stages tile kts (2 loads/phase)
  auto compute_tile = [&](int slot, bool do_stage, int kts) {
    const char* Ab = lds + slot * 32768 + wm * 8192 + lbyte;
    const char* Bb = lds + slot * 32768 + 16384 + wn * 4096 + lbyte;
    char* sbase = lds + (kts & 3) * 32768;
    const size_t ko = (size_t)kts * 32;
    // ---- sub-phase A: B-frags + A-frags q0/q1, stage A-halves ----
    f16x8 bfr[4];
#pragma unroll
    for (int fj = 0; fj < 4; ++fj) bfr[fj] = *(const f16x8*)(Bb + fj * 1024);
    f16x8 a0 = *(const f16x8*)(Ab + 0);
    f16x8 a1 = *(const f16x8*)(Ab + 1024);
    f16x8 a2 = *(const f16x8*)(Ab + 2048);
    f16x8 a3 = *(const f16x8*)(Ab + 3072);
    if (do_stage) {
      gl2lds16(A + aOff[0] + ko, sbase + t16);
      gl2lds16(A + aOff[1] + ko, sbase + 8192 + t16);
    }
    pipe_barrier();
    __builtin_amdgcn_s_setprio(1);
#pragma unroll
    for (int fj = 0; fj < 4; ++fj) {
      acc[0][fj] = __builtin_amdgcn_mfma_f32_16x16x32_f16(a0, bfr[fj], acc[0][fj], 0, 0, 0);
      acc[1][fj] = __builtin_amdgcn_mfma_f32_16x16x32_f16(a1, bfr[fj], acc[1][fj], 0, 0, 0);
      acc[2][fj] = __builtin_amdgcn_mfma_f32_16x16x32_f16(a2, bfr[fj], acc[2][fj], 0, 0, 0);
      acc[3][fj] = __builtin_amdgcn_mfma_f32_16x16x32_f16(a3, bfr[fj], acc[3][fj], 0, 0, 0);
    }
    __builtin_amdgcn_s_setprio(0);
    pipe_barrier();
    // ---- sub-phase B: A-frags q2/q3, stage B-halves ----
    f16x8 a4 = *(const f16x8*)(Ab + 4096);
    f16x8 a5 = *(const f16x8*)(Ab + 5120);
    f16x8 a6 = *(const f16x8*)(Ab + 6144);
    f16x8 a7 = *(const f16x8*)(Ab + 7168);
    if (do_stage) {
      gl2lds16(Bm + bOff[0] + ko, sbase + 16384 + t16);
      gl2lds16(Bm + bOff[1] + ko, sbase + 16384 + 8192 + t16);
    }
    pipe_barrier();
    __builtin_amdgcn_s_setprio(1);
#pragma unroll
    for (int fj = 0; fj < 4; ++fj) {
      acc[4][fj] = __builtin_amdgcn_mfma_f32_16x16x32_f16(a4, bfr[fj], acc[4][fj], 0, 0, 0);
      acc[5][fj] = __builtin_amdgcn_mfma_f32_16x16x32_f16(a5, bfr[fj], acc[5][fj], 0, 0, 0);
      acc[6][fj] = __builtin_amdgcn_mfma_f32_16x16x32_f16(a6, bfr[fj], acc[6][fj], 0, 0, 0);
      acc[7][fj] = __builtin_amdgcn_mfma_f32_16x16x32_f16(a7, bfr[fj], acc[7][fj], 0, 0, 0);
    }
    __builtin_amdgcn_s_setprio(0);
    // caller does wait_vm + pipe_barrier (tile end)
  };

  // prologue: stage tiles 0,1,2 (12 loads/thread); wait tile0 (vmcnt 8 left)
  stage_tile(0);
  stage_tile(1);
  stage_tile(2);
  wait_vm<8>();
  pipe_barrier();

  // steady state: loads for tiles kt+2, kt+3 stay in flight across barriers
  for (int kt = 0; kt <= NT - 4; ++kt) {
    compute_tile(kt & 3, true, kt + 3);
    wait_vm<8>();        // tile kt+1 landed; {kt+2, kt+3} outstanding
    pipe_barrier();
  }
  // tail: NT-3, NT-2, NT-1
  compute_tile((NT - 3) & 3, false, 0); wait_vm<4>(); pipe_barrier();
  compute_tile((NT - 2) & 3, false, 0); wait_vm<0>(); pipe_barrier();
  compute_tile((NT - 1) & 3, false, 0); pipe_barrier();

  // ---- epilogue ----
  const int col = lane & 15;
  const int rb = (lane >> 4) * 4;
  if constexpr (MODE == 0) {
#pragma unroll
    for (int fi = 0; fi < 8; ++fi)
#pragma unroll
      for (int fj = 0; fj < 4; ++fj)
#pragma unroll
        for (int r = 0; r < 4; ++r) {
          size_t gr = bm + wm * 128 + fi * 16 + rb + r;   // row in (B*N)
          size_t gc = bn + wn * 64 + fj * 16 + col;       // out channel
          Cout[gr * 2048 + gc] = acc[fi][fj][r];
        }
  } else {
    // (1) quantize to fp16, stash in wave-private 16KB LDS (XOR-swizzled),
    //     and accumulate chunk partials of q^2
    char* W = lds + wid * 16384;
#pragma unroll
    for (int fj = 0; fj < 4; ++fj) {
      float ss = 0.f;
#pragma unroll
      for (int fi = 0; fi < 8; ++fi)
#pragma unroll
        for (int r = 0; r < 4; ++r) {
          int row_l = fi * 16 + rb + r;           // 0..127
          int d_l = fj * 16 + col;                // 0..63
          f16 q = (f16)acc[fi][fj][r];
          *(f16*)(W + row_l * 128 +
                  ((d_l * 2) ^ (((row_l >> 2) & 3) << 5))) = q;
          float qf = (float)q;
          ss += qf * qf;
        }
      ss += __shfl_xor(ss, 16);
      ss += __shfl_xor(ss, 32);
      if (lane < 16) {
        int b = (int)(bm >> 11);
        int h = (int)(bn >> 7) + (wn >> 1);
        int chunk = (int)((bm & 2047) >> 7) + wm;
        int d = (wn & 1) * 64 + fj * 16 + lane;
        psum[(((size_t)(b * 16 + h)) * 16 + chunk) * 128 + d] = ss;
      }
    }
    asm volatile("s_waitcnt lgkmcnt(0)" ::: "memory");
    __builtin_amdgcn_sched_barrier(0);
    // (2) read back f16x8 per lane -> 128B-coalesced stores. Address XOR
    // compensates the stored involution (verified r8).
#pragma unroll
    for (int it = 0; it < 16; ++it) {
      int row_l = it * 8 + (lane >> 3);
      int g2 = (row_l >> 2) & 3;
      int c_p = lane & 7;
      f16x8 v = *(const f16x8*)(W + row_l * 128 + ((c_p * 16) ^ (g2 << 5)));
      size_t gr = bm + wm * 128 + row_l;
      int h = (int)(bn >> 7) + (wn >> 1);
      int d = (wn & 1) * 64 + c_p * 8;
      *(f16x8*)(Wout + (((gr >> 11) * 16 + h) * 2048 + (gr & 2047)) * 128 + d) =
          v;
    }
  }
}

// XOR-swizzled LDS index (64KB tile, conflict-free both phases)
__device__ __forceinline__ int swz(int i, int j) { return i * 128 + (j ^ (i & 31)); }

// replay chunk scan with inline exclusive prefix of raw psum (chunks < mine):
// ratio = q^2/max(cum,eps); tmp[b,h,n] = (sum_d ratio + D*bias)*temp
__global__ __launch_bounds__(128) void k_tmp(const f16* __restrict__ w,
                                             const float* __restrict__ psum,
                                             const float* __restrict__ dbias,
                                             const float* __restrict__ temp,
                                             float* __restrict__ tmp) {
  __shared__ float ratio[128 * 128];
  int blk = blockIdx.x;
  int bh = blk >> 4, chunk = blk & 15;
  int h = bh & 15;
  int d = threadIdx.x;
  float cum = 0.f;
  for (int c = 0; c < chunk; ++c)
    cum += psum[((size_t)bh * 16 + c) * 128 + d];
  const f16* base =
      w + ((size_t)bh * 2048 + (size_t)chunk * 128) * 128 + d;
  for (int i = 0; i < 128; ++i) {
    float v = (float)base[(size_t)i * 128];
    float sq = v * v;
    cum += sq;
    float dn = fmaxf(cum, EPS_F16);
    ratio[swz(i, d)] = sq / dn;
  }
  __syncthreads();
  float s = 0.f;
#pragma unroll 8
  for (int j = 0; j < 128; ++j) s += ratio[swz(d, j)];
  int n = chunk * 128 + d;
  tmp[(size_t)bh * 2048 + n] = (s + 128.f * dbias[h * 2048 + n]) * temp[h];
}

// softmax over H=16 heads. 16384 threads, one per (b,n).
__global__ __launch_bounds__(256) void k_softmax(const float* __restrict__ tmp,
                                                 float* __restrict__ Pi) {
  int idx = blockIdx.x * 256 + threadIdx.x;  // b*2048 + n
  int b = idx >> 11, n = idx & 2047;
  float v[16];
  float mx = -1e30f;
#pragma unroll
  for (int h = 0; h < 16; ++h) {
    v[h] = tmp[((size_t)(b * 16 + h)) * 2048 + n];
    mx = fmaxf(mx, v[h]);
  }
  float s = 0.f;
#pragma unroll
  for (int h = 0; h < 16; ++h) {
    v[h] = expf(v[h] - mx);
    s += v[h];
  }
  float inv = 1.f / s;
#pragma unroll
  for (int h = 0; h < 16; ++h)
    Pi[((size_t)(b * 16 + h)) * 2048 + n] = v[h] * inv;
}

// pass C: chunk partials of q^2*Pi (per d) and Pi (scalar)
__global__ __launch_bounds__(128) void k_partial2(const f16* __restrict__ w,
                                                  const float* __restrict__ Pi,
                                                  float* __restrict__ psum,
                                                  float* __restrict__ pisum) {
  int blk = blockIdx.x;
  int bh = blk >> 4, chunk = blk & 15;
  int d = threadIdx.x;
  const f16* base =
      w + ((size_t)bh * 2048 + (size_t)chunk * 128) * 128 + d;
  const float* pib = Pi + (size_t)bh * 2048 + (size_t)chunk * 128;
  float s = 0.f, sp = 0.f;
#pragma unroll 4
  for (int i = 0; i < 128; ++i) {
    float p = pib[i];
    float v = (float)base[(size_t)i * 128];
    s += v * v * p;
    sp += p;
  }
  psum[(size_t)blk * 128 + d] = s;
  if (d == 0) pisum[blk] = sp;
}

// replay with inline exclusive prefixes of raw psum2/pisum:
// dots = cum(q^2*Pi)/(cum(Pi)+eps); y = -(q*Pi)/(1+dots), fp16, (B,N,C)
__global__ __launch_bounds__(128) void k_y(const f16* __restrict__ w,
                                           const float* __restrict__ Pi,
                                           const float* __restrict__ psum2,
                                           const float* __restrict__ pisum,
                                           f16* __restrict__ yout) {
  int blk = blockIdx.x;
  int bh = blk >> 4, chunk = blk & 15;
  int b = bh >> 4, h = bh & 15;
  int d = threadIdx.x;
  float cum = 0.f, cpi = 0.f;
  for (int c = 0; c < chunk; ++c) {
    cum += psum2[((size_t)bh * 16 + c) * 128 + d];
    cpi += pisum[bh * 16 + c];
  }
  const f16* base =
      w + ((size_t)bh * 2048 + (size_t)chunk * 128) * 128 + d;
  const float* pib = Pi + (size_t)bh * 2048 + (size_t)chunk * 128;
  for (int i = 0; i < 128; ++i) {
    float p = pib[i];
    float v = (float)base[(size_t)i * 128];
    cum += v * v * p;
    cpi += p;
    float dots = cum / (cpi + EPS_F16);
    float attn = 1.f / (1.f + dots);
    float y = -(v * p) * attn;
    int n = chunk * 128 + i;
    yout[((size_t)(b * 2048 + n)) * 2048 + h * 128 + d] = (f16)y;
  }
}

// ---------------- launcher ----------------
extern "C" void kernel_launch(void* const* d_in, const int* in_sizes, int n_in,
                              void* d_out, int out_size, void* d_ws, size_t ws_size,
                              hipStream_t stream) {
  const float* x     = (const float*)d_in[0];
  const float* Wa    = (const float*)d_in[1];
  const float* Wp    = (const float*)d_in[2];
  const float* temp  = (const float*)d_in[3];
  const float* dbias = (const float*)d_in[4];
  float* out = (float*)d_out;

  char* ws = (char*)d_ws;
  // workspace layout (bytes)
  constexpr size_t OFF_W   = 0;                        // w fp16 (B,H,N,D): 67108864
  constexpr size_t OFF_XH  = 67108864;                 // x fp16 (reused as y fp16): 67108864
  constexpr size_t OFF_WAH = OFF_XH + 67108864;        // W_attn fp16: 8388608
  constexpr size_t OFF_WPB = OFF_WAH + 8388608;        // W_proj fp16: 8388608
  constexpr size_t OFF_TMP = OFF_WPB + 8388608;        // tmp (B,H,N) fp32
  constexpr size_t OFF_PI  = OFF_TMP + 2097152;        // Pi  (B,H,N) fp32
  constexpr size_t OFF_PS  = OFF_PI + 2097152;         // chunk partials
  constexpr size_t OFF_PIS = OFF_PS + 1048576;         // Pi chunk partials

  f16*   w    = (f16*)(ws + OFF_W);
  f16*   xh   = (f16*)(ws + OFF_XH);   // later reused as y (fp16)
  f16*   Wah  = (f16*)(ws + OFF_WAH);
  f16*   Wpb  = (f16*)(ws + OFF_WPB);
  float* tmp  = (float*)(ws + OFF_TMP);
  float* Pi   = (float*)(ws + OFF_PI);
  float* psum = (float*)(ws + OFF_PS);
  float* pis  = (float*)(ws + OFF_PIS);

  // casts
  k_cast8h<<<16384, 256, 0, stream>>>(x, xh, 4194304LL);
  k_cast8h<<<2048, 256, 0, stream>>>(Wa, Wah, 524288LL);
  k_cast8h<<<2048, 256, 0, stream>>>(Wp, Wpb, 524288LL);

  // GEMM1 (fp16, 256^2, 4-slot counted-vmcnt + 2-sub-phase interleave)
  gemm256<1><<<dim3(8, 64), 512, 0, stream>>>(xh, Wah, nullptr, w, psum);

  // scan A (prefix folded into k_tmp)
  k_tmp<<<2048, 128, 0, stream>>>(w, psum, dbias, temp, tmp);

  // softmax over heads
  k_softmax<<<64, 256, 0, stream>>>(tmp, Pi);

  // scan C: partials, then replay with inline prefix -> y (fp16, reuses xh)
  k_partial2<<<2048, 128, 0, stream>>>(w, Pi, psum, pis);
  k_y<<<2048, 128, 0, stream>>>(w, Pi, psum, pis, xh);

  // GEMM2 (fp16, 256^2, 4-slot counted-vmcnt + 2-sub-phase interleave)
  gemm256<0><<<dim3(8, 64), 512, 0, stream>>>(xh, Wpb, out, nullptr, nullptr);
}